// Round 13
// baseline (302.690 us; speedup 1.0000x reference)
//
#include <hip/hip_runtime.h>

// ---------------------------------------------------------------------------
// GRACE GCN 2-layer forward, CSR-gather, bf16 intermediates, SLICE-PLANAR:
//   h1' = (X W1) * dinv    stored as 8 planar n x 16 bf16 slices (3.2 MB each)
//   h2  = prelu(...)       8 slices;  g' = (h2 W2) * dinv  -> 4 slices
//   out = prelu(...)       f32 [n][64]
// R12->R13: aggregation runs one dispatch PER SLICE (12 total). A 3.2 MB
// slice fits every XCD's private 4 MB L2 -> random gathers become L2-hits
// (R8/R10: FETCH ~7.2x array size = every XCD missing on a 12.8 MB set).
// GEMMs write/read slices with compile-time slice indices.
// ---------------------------------------------------------------------------

#define THREADS 256
#define SCAN_CHUNK 1024   // 256 threads x 4 elements
#define NBLK  256         // partition blocks (fixed chunking)
#define BINSH 7           // 128 nodes per bin
#define BINSZ 128
#define KMAX  1024        // max bins (supports n <= 131072)

typedef unsigned short bf16_t;
typedef __attribute__((ext_vector_type(8))) short bf16x8;
typedef __attribute__((ext_vector_type(4))) float f32x4;

struct CPtr8 { const bf16_t* p[8]; };
struct Ptr8  { bf16_t* p[8]; };

__device__ __forceinline__ float bflo(unsigned int w) {
    union { unsigned int u; float f; } v; v.u = w << 16; return v.f;
}
__device__ __forceinline__ float bfhi(unsigned int w) {
    union { unsigned int u; float f; } v; v.u = w & 0xffff0000u; return v.f;
}
__device__ __forceinline__ unsigned int f2bf(float f) {  // RNE
    union { float f; unsigned int u; } v; v.f = f;
    return (v.u + 0x7fffu + ((v.u >> 16) & 1u)) >> 16;
}

// -------------------- pass 1: per-block bin histogram --------------------
__global__ __launch_bounds__(THREADS) void hist_kernel(const int* __restrict__ dst,
                                                       int* __restrict__ hist,
                                                       int e, int K, int chunk) {
    __shared__ int h[KMAX];
    int t = threadIdx.x, b = blockIdx.x;
    for (int i = t; i < K; i += THREADS) h[i] = 0;
    __syncthreads();
    int lo = b * chunk, hi = min(lo + chunk, e);
    for (int i = lo + t; i < hi; i += THREADS) atomicAdd(&h[dst[i] >> BINSH], 1);
    __syncthreads();
    for (int i = t; i < K; i += THREADS) hist[i * NBLK + b] = h[i];  // bin-major
}

// -------------------- exclusive scan over m elements (3 phases) ------------
__global__ void scan_phaseA_kernel(const int* __restrict__ in, int* __restrict__ bsum, int m) {
    __shared__ int sdata[256];
    int base = blockIdx.x * SCAN_CHUNK;
    int t = threadIdx.x;
    int s = 0;
#pragma unroll
    for (int k = 0; k < 4; ++k) {
        int idx = base + t * 4 + k;
        if (idx < m) s += in[idx];
    }
    sdata[t] = s;
    __syncthreads();
    for (int d = 128; d > 0; d >>= 1) {
        if (t < d) sdata[t] += sdata[t + d];
        __syncthreads();
    }
    if (t == 0) bsum[blockIdx.x] = sdata[0];
}

__global__ void scan_phaseB_kernel(int* __restrict__ bsum, int nb) {
    __shared__ int sdata[256];
    __shared__ int carry;
    int t = threadIdx.x;
    if (t == 0) carry = 0;
    __syncthreads();
    for (int base = 0; base < nb; base += 256) {
        int idx = base + t;
        int v = (idx < nb) ? bsum[idx] : 0;
        sdata[t] = v;
        __syncthreads();
        for (int d = 1; d < 256; d <<= 1) {
            int u = (t >= d) ? sdata[t - d] : 0;
            __syncthreads();
            sdata[t] += u;
            __syncthreads();
        }
        int excl = sdata[t] - v + carry;
        if (idx < nb) bsum[idx] = excl;
        int tot = sdata[255];
        __syncthreads();
        if (t == 0) carry += tot;
        __syncthreads();
    }
}

__global__ void scan_phaseC_kernel(const int* __restrict__ in, const int* __restrict__ bsum,
                                   int* __restrict__ outx, int m) {
    __shared__ int sdata[256];
    int base = blockIdx.x * SCAN_CHUNK;
    int t = threadIdx.x;
    int v[4];
    int s = 0;
#pragma unroll
    for (int k = 0; k < 4; ++k) {
        int idx = base + t * 4 + k;
        v[k] = (idx < m) ? in[idx] : 0;
        s += v[k];
    }
    sdata[t] = s;
    __syncthreads();
    for (int d = 1; d < 256; d <<= 1) {
        int u = (t >= d) ? sdata[t - d] : 0;
        __syncthreads();
        sdata[t] += u;
        __syncthreads();
    }
    int run = bsum[blockIdx.x] + sdata[t] - s;  // exclusive base
#pragma unroll
    for (int k = 0; k < 4; ++k) {
        int idx = base + t * 4 + k;
        if (idx < m) { outx[idx] = run; run += v[k]; }
    }
}

// -------------------- pass 2: rank via LDS + scatter to (bin,blk) segment ---
__global__ __launch_bounds__(THREADS) void rank_scatter_kernel(const int* __restrict__ src,
                                                               const int* __restrict__ dst,
                                                               const int* __restrict__ hoff,
                                                               unsigned int* __restrict__ sorted,
                                                               int e, int K, int chunk) {
    __shared__ int cntl[KMAX];
    __shared__ int basel[KMAX];
    int t = threadIdx.x, b = blockIdx.x;
    for (int i = t; i < K; i += THREADS) { cntl[i] = 0; basel[i] = hoff[i * NBLK + b]; }
    __syncthreads();
    int lo = b * chunk, hi = min(lo + chunk, e);
    for (int i = lo + t; i < hi; i += THREADS) {
        int d = dst[i];
        int bin = d >> BINSH;
        int r = atomicAdd(&cntl[bin], 1);
        sorted[basel[bin] + r] = (unsigned int)src[i] | ((unsigned int)(d & (BINSZ - 1)) << 25);
    }
}

// -------------------- pass 3: per-bin counting sort -> exact CSR ------------
__global__ __launch_bounds__(THREADS) void bin_build_kernel(const unsigned int* __restrict__ sorted,
                                                            const int* __restrict__ hoff,
                                                            float* __restrict__ dinv,
                                                            int* __restrict__ off,
                                                            int* __restrict__ cnt,
                                                            int* __restrict__ es,
                                                            int n, int e, int K) {
    __shared__ int scnt[BINSZ];
    __shared__ int soff[BINSZ];
    int b = blockIdx.x, t = threadIdx.x;
    int base = hoff[b * NBLK];
    int end  = (b + 1 < K) ? hoff[(b + 1) * NBLK] : e;
    int m = end - base;
    if (t < BINSZ) scnt[t] = 0;
    __syncthreads();
    for (int i = t; i < m; i += THREADS) atomicAdd(&scnt[sorted[base + i] >> 25], 1);
    __syncthreads();
    if (t < BINSZ) soff[t] = scnt[t];
    __syncthreads();
    for (int d = 1; d < BINSZ; d <<= 1) {
        int v = (t < BINSZ && t >= d) ? soff[t - d] : 0;
        __syncthreads();
        if (t < BINSZ) soff[t] += v;
        __syncthreads();
    }
    if (t < BINSZ) {
        int ex = soff[t] - scnt[t];     // exclusive
        int node = (b << BINSH) + t;
        if (node < n) {
            off[node]  = base + ex;
            cnt[node]  = scnt[t];
            dinv[node] = rsqrtf((float)(scnt[t] + 1));  // +1 self loop
        }
        soff[t] = ex;                   // local cursor
    }
    __syncthreads();
    for (int i = t; i < m; i += THREADS) {
        unsigned int pk = sorted[base + i];
        int pos = atomicAdd(&soff[pk >> 25], 1);
        es[base + pos] = (int)(pk & 0x01FFFFFFu);
    }
}

// ---- W transposes (both weights, one dispatch): WT[c][k] = bf16(W[k][c]) ---
__global__ void wt2_kernel(const float* __restrict__ W1, bf16_t* __restrict__ WT1,
                           const float* __restrict__ W2, bf16_t* __restrict__ WT2,
                           int K1, int C1, int K2, int C2) {
    int tid = blockIdx.x * blockDim.x + threadIdx.x;
    int t1 = K1 * C1;
    if (tid < t1) {
        int c = tid / K1, k = tid % K1;
        WT1[(size_t)c * K1 + k] = (bf16_t)f2bf(W1[(size_t)k * C1 + c]);
    } else if (tid < t1 + K2 * C2) {
        int id = tid - t1;
        int c = id / K2, k = id % K2;
        WT2[(size_t)c * K2 + k] = (bf16_t)f2bf(W2[(size_t)k * C2 + c]);
    }
}

// -------------------- MFMA GEMM -> slice-planar output ----------------------
// D = mfma(W_frag, X_frag): lane owns 4 consecutive output cols (kgrp*4+reg)
// of row (tile + lane&15); slice == ct (16 cols) -> compile-time slice ptr,
// packed uint2 stores. 2 row-tiles/wave, 4 waves/block (128 rows/block).
// XSLICE: X read from 8 planar n x 16 slices (slice = ks*2 + (kgrp>>1)).
template <int OUTC, bool XBF, bool XSLICE>
__global__ __launch_bounds__(THREADS) void gemm_mfma_kernel(const void* __restrict__ Xv,
                                                            CPtr8 xs,
                                                            const bf16_t* __restrict__ WT,
                                                            const float* __restrict__ rowscale,
                                                            Ptr8 os, int n) {
    constexpr int CT = OUTC / 16;            // col tiles == output slices
    constexpr int RT = 2;                    // row tiles per wave
    int wid  = (int)threadIdx.x >> 6;
    int lane = (int)threadIdx.x & 63;
    int col16 = lane & 15;
    int kgrp  = lane >> 4;                   // 0..3
    int rbase = blockIdx.x * (4 * RT * 16) + wid * (RT * 16);

    // ---- X fragments + rowscale for RT row-tiles (all loads up-front) ----
    int row[RT];
    float sc[RT];
    bf16x8 xf[RT][4];
#pragma unroll
    for (int rt = 0; rt < RT; ++rt) {
        row[rt] = rbase + rt * 16 + col16;
        int rc = row[rt] < n ? row[rt] : (n - 1);   // clamp loads; stores guarded
        sc[rt] = rowscale[rc];
#pragma unroll
        for (int ks = 0; ks < 4; ++ks) {
            int kb = ks * 32 + kgrp * 8;
            if constexpr (XSLICE) {
                const bf16_t* xb = (kgrp < 2) ? xs.p[ks * 2] : xs.p[ks * 2 + 1];
                xf[rt][ks] = *reinterpret_cast<const bf16x8*>(xb + (size_t)rc * 16 + (kgrp & 1) * 8);
            } else if constexpr (XBF) {
                xf[rt][ks] = *reinterpret_cast<const bf16x8*>((const bf16_t*)Xv + (size_t)rc * 128 + kb);
            } else {
                const float* xp = (const float*)Xv + (size_t)rc * 128 + kb;
                float4 x0 = *reinterpret_cast<const float4*>(xp);
                float4 x1 = *reinterpret_cast<const float4*>(xp + 4);
                bf16x8 t;
                t[0] = (short)f2bf(x0.x); t[1] = (short)f2bf(x0.y);
                t[2] = (short)f2bf(x0.z); t[3] = (short)f2bf(x0.w);
                t[4] = (short)f2bf(x1.x); t[5] = (short)f2bf(x1.y);
                t[6] = (short)f2bf(x1.z); t[7] = (short)f2bf(x1.w);
                xf[rt][ks] = t;
            }
        }
    }

    // ---- per col-tile: load W frags once, 2 row-tiles of MFMA, packed store -
#pragma unroll
    for (int ct = 0; ct < CT; ++ct) {
        const bf16_t* wp = WT + (size_t)(ct * 16 + col16) * 128 + kgrp * 8;
        bf16x8 wf[4];
#pragma unroll
        for (int ks = 0; ks < 4; ++ks) wf[ks] = *reinterpret_cast<const bf16x8*>(wp + ks * 32);
#pragma unroll
        for (int rt = 0; rt < RT; ++rt) {
            f32x4 acc = {0.f, 0.f, 0.f, 0.f};
#pragma unroll
            for (int ks = 0; ks < 4; ++ks)
                acc = __builtin_amdgcn_mfma_f32_16x16x32_bf16(wf[ks], xf[rt][ks], acc, 0, 0, 0);
            if (row[rt] < n) {
                float s = sc[rt];
                uint2 w;
                w.x = f2bf(acc[0] * s) | (f2bf(acc[1] * s) << 16);
                w.y = f2bf(acc[2] * s) | (f2bf(acc[3] * s) << 16);
                *reinterpret_cast<uint2*>(os.p[ct] + (size_t)row[rt] * 16 + kgrp * 4) = w;
            }
        }
    }
}

// -------------------- CSR aggregate over ONE 16-col slice -------------------
// out[i, ocol..ocol+16) = prelu( dinv[i]*(H[i,:] + sum_j H[es[j],:]) + b, a )
// H: planar n x 16 bf16 slice (3.2 MB -> per-XCD L2-resident). TPN=2.
template <bool OUTBF>
__global__ __launch_bounds__(THREADS) void agg_kernel(const bf16_t* __restrict__ H,
                                                      const float* __restrict__ dinv,
                                                      const int* __restrict__ off,
                                                      const int* __restrict__ cnt,
                                                      const int* __restrict__ es,
                                                      const float* __restrict__ bias,
                                                      const float* __restrict__ a_ptr,
                                                      void* __restrict__ outv,
                                                      int ocol, int ostride, int n) {
    int node = blockIdx.x * 128 + ((int)threadIdx.x >> 1);
    int l8   = (int)threadIdx.x & 1;
    if (node >= n) return;
    const int fbase = l8 * 8;

    float acc[8];
    {   // self term (H already pre-scaled by dinv[node])
        uint4 v = *reinterpret_cast<const uint4*>(H + (size_t)node * 16 + fbase);
        acc[0] = bflo(v.x); acc[1] = bfhi(v.x);
        acc[2] = bflo(v.y); acc[3] = bfhi(v.y);
        acc[4] = bflo(v.z); acc[5] = bfhi(v.z);
        acc[6] = bflo(v.w); acc[7] = bfhi(v.w);
    }

    int j0 = off[node];
    int m  = cnt[node];
    int i = 0;
    for (; i + 3 < m; i += 4) {
        int s0 = es[j0 + i], s1 = es[j0 + i + 1], s2 = es[j0 + i + 2], s3 = es[j0 + i + 3];
        uint4 v0 = *reinterpret_cast<const uint4*>(H + (size_t)s0 * 16 + fbase);
        uint4 v1 = *reinterpret_cast<const uint4*>(H + (size_t)s1 * 16 + fbase);
        uint4 v2 = *reinterpret_cast<const uint4*>(H + (size_t)s2 * 16 + fbase);
        uint4 v3 = *reinterpret_cast<const uint4*>(H + (size_t)s3 * 16 + fbase);
        acc[0] += (bflo(v0.x) + bflo(v1.x)) + (bflo(v2.x) + bflo(v3.x));
        acc[1] += (bfhi(v0.x) + bfhi(v1.x)) + (bfhi(v2.x) + bfhi(v3.x));
        acc[2] += (bflo(v0.y) + bflo(v1.y)) + (bflo(v2.y) + bflo(v3.y));
        acc[3] += (bfhi(v0.y) + bfhi(v1.y)) + (bfhi(v2.y) + bfhi(v3.y));
        acc[4] += (bflo(v0.z) + bflo(v1.z)) + (bflo(v2.z) + bflo(v3.z));
        acc[5] += (bfhi(v0.z) + bfhi(v1.z)) + (bfhi(v2.z) + bfhi(v3.z));
        acc[6] += (bflo(v0.w) + bflo(v1.w)) + (bflo(v2.w) + bflo(v3.w));
        acc[7] += (bfhi(v0.w) + bfhi(v1.w)) + (bfhi(v2.w) + bfhi(v3.w));
    }
    for (; i < m; ++i) {
        int s0 = es[j0 + i];
        uint4 v0 = *reinterpret_cast<const uint4*>(H + (size_t)s0 * 16 + fbase);
        acc[0] += bflo(v0.x); acc[1] += bfhi(v0.x);
        acc[2] += bflo(v0.y); acc[3] += bfhi(v0.y);
        acc[4] += bflo(v0.z); acc[5] += bfhi(v0.z);
        acc[6] += bflo(v0.w); acc[7] += bfhi(v0.w);
    }

    float di = dinv[node];
    float a  = *a_ptr;
    float4 b0 = *reinterpret_cast<const float4*>(bias + fbase);
    float4 b1 = *reinterpret_cast<const float4*>(bias + fbase + 4);
    float bb[8] = {b0.x, b0.y, b0.z, b0.w, b1.x, b1.y, b1.z, b1.w};
    float o[8];
#pragma unroll
    for (int k = 0; k < 8; ++k) {
        float v = acc[k] * di + bb[k];
        o[k] = v >= 0.f ? v : a * v;
    }

    if constexpr (OUTBF) {
        uint4 w;
        w.x = f2bf(o[0]) | (f2bf(o[1]) << 16);
        w.y = f2bf(o[2]) | (f2bf(o[3]) << 16);
        w.z = f2bf(o[4]) | (f2bf(o[5]) << 16);
        w.w = f2bf(o[6]) | (f2bf(o[7]) << 16);
        *reinterpret_cast<uint4*>((bf16_t*)outv + (size_t)node * ostride + ocol + fbase) = w;
    } else {
        float* op = (float*)outv + (size_t)node * ostride + ocol + fbase;
        *reinterpret_cast<float4*>(op)     = make_float4(o[0], o[1], o[2], o[3]);
        *reinterpret_cast<float4*>(op + 4) = make_float4(o[4], o[5], o[6], o[7]);
    }
}

extern "C" void kernel_launch(void* const* d_in, const int* in_sizes, int n_in,
                              void* d_out, int out_size, void* d_ws, size_t ws_size,
                              hipStream_t stream) {
    const float* x   = (const float*)d_in[0];
    const int*   ei  = (const int*)d_in[1];
    const float* W1  = (const float*)d_in[2];
    const float* b1  = (const float*)d_in[3];
    const float* W2  = (const float*)d_in[4];
    const float* b2  = (const float*)d_in[5];
    const float* a   = (const float*)d_in[6];

    const int IN  = 128;
    const int HID = 128;
    const int OUT = 64;
    const int n = in_sizes[0] / IN;       // 100000
    const int e = in_sizes[1] / 2;        // 1600000
    const int* src = ei;
    const int* dst = ei + e;

    const int K     = (n + BINSZ - 1) >> BINSH;   // 782 bins
    const int chunk = (e + NBLK - 1) / NBLK;      // 6250 edges/block
    const int M     = K * NBLK;                   // ~200k hist entries
    const int nb    = (M + SCAN_CHUNK - 1) / SCAN_CHUNK;

    auto align = [](size_t v) { return (v + 255) / 256 * 256; };
    char* ws = (char*)d_ws;
    size_t o = 0;
    int*          hist   = (int*)(ws + o);          o += align((size_t)M * 4);
    int*          hoff   = (int*)(ws + o);          o += align((size_t)M * 4);
    int*          bsum   = (int*)(ws + o);          o += align((size_t)nb * 4);
    unsigned int* sorted = (unsigned int*)(ws + o); o += align((size_t)e * 4);
    int*          es     = (int*)(ws + o);          o += align((size_t)e * 4);
    float*        dinv   = (float*)(ws + o);        o += align((size_t)n * 4);
    int*          off    = (int*)(ws + o);          o += align((size_t)n * 4);
    int*          cnt    = (int*)(ws + o);          o += align((size_t)n * 4);
    Ptr8 h1s, h2s, gs;
    for (int s = 0; s < 8; ++s) { h1s.p[s] = (bf16_t*)(ws + o); o += align((size_t)n * 16 * 2); }
    for (int s = 0; s < 8; ++s) { h2s.p[s] = (bf16_t*)(ws + o); o += align((size_t)n * 16 * 2); }
    for (int s = 0; s < 8; ++s) { gs.p[s]  = (s < 4) ? (bf16_t*)(ws + o) : nullptr;
                                  if (s < 4) o += align((size_t)n * 16 * 2); }
    bf16_t*       WT1    = (bf16_t*)(ws + o);       o += align((size_t)IN * HID * 2);
    bf16_t*       WT2    = (bf16_t*)(ws + o);       o += align((size_t)HID * OUT * 2);

    float* out = (float*)d_out;
    CPtr8 h2c; for (int s = 0; s < 8; ++s) h2c.p[s] = h2s.p[s];
    CPtr8 nullc = {};

    // ---- W transposes (one dispatch, independent of CSR chain) ----
    {
        int tot = IN * HID + HID * OUT;
        wt2_kernel<<<(tot + THREADS - 1) / THREADS, THREADS, 0, stream>>>(
            W1, WT1, W2, WT2, IN, HID, HID, OUT);
    }

    // ---- CSR build: radix partition + per-bin counting sort ----
    hist_kernel<<<NBLK, THREADS, 0, stream>>>(dst, hist, e, K, chunk);
    scan_phaseA_kernel<<<nb, THREADS, 0, stream>>>(hist, bsum, M);
    scan_phaseB_kernel<<<1, THREADS, 0, stream>>>(bsum, nb);
    scan_phaseC_kernel<<<nb, THREADS, 0, stream>>>(hist, bsum, hoff, M);
    rank_scatter_kernel<<<NBLK, THREADS, 0, stream>>>(src, dst, hoff, sorted, e, K, chunk);
    bin_build_kernel<<<K, THREADS, 0, stream>>>(sorted, hoff, dinv, off, cnt, es, n, e, K);

    int gbG = (n + 127) / 128;                 // 128 rows/block (4 waves x 32)
    int gbA = (n + 127) / 128;                 // 128 nodes/block for slice agg

    // ---- layer 1: GEMM -> 8 slices; 8 slice-aggregations ----
    gemm_mfma_kernel<128, false, false><<<gbG, THREADS, 0, stream>>>(
        x, nullc, WT1, dinv, h1s, n);
    for (int s = 0; s < 8; ++s)
        agg_kernel<true><<<gbA, THREADS, 0, stream>>>(
            h1s.p[s], dinv, off, cnt, es, b1 + s * 16, a, h2s.p[s], 0, 16, n);

    // ---- layer 2: GEMM (slice inputs) -> 4 slices; 4 slice-aggregations ----
    gemm_mfma_kernel<64, true, true><<<gbG, THREADS, 0, stream>>>(
        nullptr, h2c, WT2, dinv, gs, n);
    for (int s = 0; s < 4; ++s)
        agg_kernel<false><<<gbA, THREADS, 0, stream>>>(
            gs.p[s], dinv, off, cnt, es, b2 + s * 16, a, out, s * 16, 64, n);

    (void)ws_size; (void)n_in; (void)out_size;
}

// Round 14
// 187.111 us; speedup vs baseline: 1.6177x; 1.6177x over previous
//
#include <hip/hip_runtime.h>

// ---------------------------------------------------------------------------
// GRACE GCN 2-layer forward, CSR-gather formulation, bf16 intermediates.
//   h1' = (X W1) * dinv      (bf16, planar-split halves, MFMA bf16)
//   h2  = prelu(dinv_d*(h1'_d + sum_j h1'_es[j]) + b1)    (bf16, split halves)
//   g'  = (h2 W2) * dinv     (bf16, MFMA reading split halves)
//   out = prelu(dinv_d*(g'_d + sum_j g'_es[j]) + b2)      (f32)
// R13->R14: slice-planar agg REVERTED (regressed 197->303: per-edge loop
// overhead amortized over 16B instead of 128B swamped any L2 gain). Back to
// R12 structure. CSR chain: hist/rank_scatter/bin_build now 1024 thr/block
// (R13 profile: rank_scatter 39us at 8% occupancy -- latency-bound scattered
// writes with only 4 waves/CU; 4x waves hides them).
// ---------------------------------------------------------------------------

#define THREADS 256
#define RSTH 1024         // big-block size for CSR-chain kernels
#define SCAN_CHUNK 1024   // 256 threads x 4 elements
#define NBLK  256         // partition blocks (fixed chunking)
#define BINSH 7           // 128 nodes per bin
#define BINSZ 128
#define KMAX  1024        // max bins (supports n <= 131072)

typedef unsigned short bf16_t;
typedef __attribute__((ext_vector_type(8))) short bf16x8;
typedef __attribute__((ext_vector_type(4))) float f32x4;

__device__ __forceinline__ float bflo(unsigned int w) {
    union { unsigned int u; float f; } v; v.u = w << 16; return v.f;
}
__device__ __forceinline__ float bfhi(unsigned int w) {
    union { unsigned int u; float f; } v; v.u = w & 0xffff0000u; return v.f;
}
__device__ __forceinline__ unsigned int f2bf(float f) {  // RNE
    union { float f; unsigned int u; } v; v.f = f;
    return (v.u + 0x7fffu + ((v.u >> 16) & 1u)) >> 16;
}

// -------------------- pass 1: per-block bin histogram (1024 thr) ------------
__global__ __launch_bounds__(RSTH) void hist_kernel(const int* __restrict__ dst,
                                                    int* __restrict__ hist,
                                                    int e, int K, int chunk) {
    __shared__ int h[KMAX];
    int t = threadIdx.x, b = blockIdx.x;
    for (int i = t; i < K; i += RSTH) h[i] = 0;
    __syncthreads();
    int lo = b * chunk, hi = min(lo + chunk, e);
    for (int i = lo + t; i < hi; i += RSTH) atomicAdd(&h[dst[i] >> BINSH], 1);
    __syncthreads();
    for (int i = t; i < K; i += RSTH) hist[i * NBLK + b] = h[i];  // bin-major
}

// -------------------- exclusive scan over m elements (3 phases) ------------
__global__ void scan_phaseA_kernel(const int* __restrict__ in, int* __restrict__ bsum, int m) {
    __shared__ int sdata[256];
    int base = blockIdx.x * SCAN_CHUNK;
    int t = threadIdx.x;
    int s = 0;
#pragma unroll
    for (int k = 0; k < 4; ++k) {
        int idx = base + t * 4 + k;
        if (idx < m) s += in[idx];
    }
    sdata[t] = s;
    __syncthreads();
    for (int d = 128; d > 0; d >>= 1) {
        if (t < d) sdata[t] += sdata[t + d];
        __syncthreads();
    }
    if (t == 0) bsum[blockIdx.x] = sdata[0];
}

__global__ void scan_phaseB_kernel(int* __restrict__ bsum, int nb) {
    __shared__ int sdata[256];
    __shared__ int carry;
    int t = threadIdx.x;
    if (t == 0) carry = 0;
    __syncthreads();
    for (int base = 0; base < nb; base += 256) {
        int idx = base + t;
        int v = (idx < nb) ? bsum[idx] : 0;
        sdata[t] = v;
        __syncthreads();
        for (int d = 1; d < 256; d <<= 1) {
            int u = (t >= d) ? sdata[t - d] : 0;
            __syncthreads();
            sdata[t] += u;
            __syncthreads();
        }
        int excl = sdata[t] - v + carry;
        if (idx < nb) bsum[idx] = excl;
        int tot = sdata[255];
        __syncthreads();
        if (t == 0) carry += tot;
        __syncthreads();
    }
}

__global__ void scan_phaseC_kernel(const int* __restrict__ in, const int* __restrict__ bsum,
                                   int* __restrict__ outx, int m) {
    __shared__ int sdata[256];
    int base = blockIdx.x * SCAN_CHUNK;
    int t = threadIdx.x;
    int v[4];
    int s = 0;
#pragma unroll
    for (int k = 0; k < 4; ++k) {
        int idx = base + t * 4 + k;
        v[k] = (idx < m) ? in[idx] : 0;
        s += v[k];
    }
    sdata[t] = s;
    __syncthreads();
    for (int d = 1; d < 256; d <<= 1) {
        int u = (t >= d) ? sdata[t - d] : 0;
        __syncthreads();
        sdata[t] += u;
        __syncthreads();
    }
    int run = bsum[blockIdx.x] + sdata[t] - s;  // exclusive base
#pragma unroll
    for (int k = 0; k < 4; ++k) {
        int idx = base + t * 4 + k;
        if (idx < m) { outx[idx] = run; run += v[k]; }
    }
}

// ---------- pass 2: rank via LDS + scatter to (bin,blk) segment (1024 thr) --
__global__ __launch_bounds__(RSTH) void rank_scatter_kernel(const int* __restrict__ src,
                                                            const int* __restrict__ dst,
                                                            const int* __restrict__ hoff,
                                                            unsigned int* __restrict__ sorted,
                                                            int e, int K, int chunk) {
    __shared__ int cntl[KMAX];
    __shared__ int basel[KMAX];
    int t = threadIdx.x, b = blockIdx.x;
    for (int i = t; i < K; i += RSTH) { cntl[i] = 0; basel[i] = hoff[i * NBLK + b]; }
    __syncthreads();
    int lo = b * chunk, hi = min(lo + chunk, e);
    for (int i = lo + t; i < hi; i += RSTH) {
        int d = dst[i];
        int bin = d >> BINSH;
        int r = atomicAdd(&cntl[bin], 1);
        sorted[basel[bin] + r] = (unsigned int)src[i] | ((unsigned int)(d & (BINSZ - 1)) << 25);
    }
}

// ---------- pass 3: per-bin counting sort -> exact CSR (1024 thr) -----------
__global__ __launch_bounds__(RSTH) void bin_build_kernel(const unsigned int* __restrict__ sorted,
                                                         const int* __restrict__ hoff,
                                                         float* __restrict__ dinv,
                                                         int* __restrict__ off,
                                                         int* __restrict__ cnt,
                                                         int* __restrict__ es,
                                                         int n, int e, int K) {
    __shared__ int scnt[BINSZ];
    __shared__ int soff[BINSZ];
    int b = blockIdx.x, t = threadIdx.x;
    int base = hoff[b * NBLK];
    int end  = (b + 1 < K) ? hoff[(b + 1) * NBLK] : e;
    int m = end - base;
    if (t < BINSZ) scnt[t] = 0;
    __syncthreads();
    for (int i = t; i < m; i += RSTH) atomicAdd(&scnt[sorted[base + i] >> 25], 1);
    __syncthreads();
    if (t < BINSZ) soff[t] = scnt[t];
    __syncthreads();
    for (int d = 1; d < BINSZ; d <<= 1) {
        int v = (t < BINSZ && t >= d) ? soff[t - d] : 0;
        __syncthreads();
        if (t < BINSZ) soff[t] += v;
        __syncthreads();
    }
    if (t < BINSZ) {
        int ex = soff[t] - scnt[t];     // exclusive
        int node = (b << BINSH) + t;
        if (node < n) {
            off[node]  = base + ex;
            cnt[node]  = scnt[t];
            dinv[node] = rsqrtf((float)(scnt[t] + 1));  // +1 self loop
        }
        soff[t] = ex;                   // local cursor
    }
    __syncthreads();
    for (int i = t; i < m; i += RSTH) {
        unsigned int pk = sorted[base + i];
        int pos = atomicAdd(&soff[pk >> 25], 1);
        es[base + pos] = (int)(pk & 0x01FFFFFFu);
    }
}

// ---- W transposes (both weights, one dispatch): WT[c][k] = bf16(W[k][c]) ---
__global__ void wt2_kernel(const float* __restrict__ W1, bf16_t* __restrict__ WT1,
                           const float* __restrict__ W2, bf16_t* __restrict__ WT2,
                           int K1, int C1, int K2, int C2) {
    int tid = blockIdx.x * blockDim.x + threadIdx.x;
    int t1 = K1 * C1;
    if (tid < t1) {
        int c = tid / K1, k = tid % K1;
        WT1[(size_t)c * K1 + k] = (bf16_t)f2bf(W1[(size_t)k * C1 + c]);
    } else if (tid < t1 + K2 * C2) {
        int id = tid - t1;
        int c = id / K2, k = id % K2;
        WT2[(size_t)c * K2 + k] = (bf16_t)f2bf(W2[(size_t)k * C2 + c]);
    }
}

// -------------------- MFMA GEMM: H = (X[n,128] @ W[128,OUTC]) * rowscale ----
// Swapped operands: D = mfma(A=W_frag, B=X_frag) so D's col index = X row,
// D's row index = output col. Lane holds 4 consecutive output cols (kgrp*4 +
// reg) of row (tile + lane&15) -> packed uint2 stores. 2 row-tiles per wave
// (32 rows), 4 waves/block (128 rows/block).
// XSPLIT: X given as two planar n x 64 bf16 halves; OSPLIT: output written as
// two planar n x (OUTC/2) halves.
template <int OUTC, bool XBF, bool XSPLIT, bool OSPLIT>
__global__ __launch_bounds__(THREADS) void gemm_mfma_kernel(const void* __restrict__ Xv,
                                                            const void* __restrict__ Xv2,
                                                            const bf16_t* __restrict__ WT,
                                                            const float* __restrict__ rowscale,
                                                            bf16_t* __restrict__ H,
                                                            bf16_t* __restrict__ H2, int n) {
    constexpr int CT = OUTC / 16;            // col tiles
    constexpr int RT = 2;                    // row tiles per wave
    int wid  = (int)threadIdx.x >> 6;
    int lane = (int)threadIdx.x & 63;
    int col16 = lane & 15;
    int kgrp  = lane >> 4;                   // 0..3
    int rbase = blockIdx.x * (4 * RT * 16) + wid * (RT * 16);

    // ---- X fragments + rowscale for RT row-tiles (all loads up-front) ----
    int row[RT];
    float sc[RT];
    bf16x8 xf[RT][4];
#pragma unroll
    for (int rt = 0; rt < RT; ++rt) {
        row[rt] = rbase + rt * 16 + col16;
        int rc = row[rt] < n ? row[rt] : (n - 1);   // clamp loads; stores guarded
        sc[rt] = rowscale[rc];
#pragma unroll
        for (int ks = 0; ks < 4; ++ks) {
            int kb = ks * 32 + kgrp * 8;
            if constexpr (XBF) {
                if constexpr (XSPLIT) {
                    const bf16_t* xb = (ks < 2) ? (const bf16_t*)Xv : (const bf16_t*)Xv2;
                    xf[rt][ks] = *reinterpret_cast<const bf16x8*>(xb + (size_t)rc * 64 + (kb & 63));
                } else {
                    xf[rt][ks] = *reinterpret_cast<const bf16x8*>((const bf16_t*)Xv + (size_t)rc * 128 + kb);
                }
            } else {
                const float* xp = (const float*)Xv + (size_t)rc * 128 + kb;
                float4 x0 = *reinterpret_cast<const float4*>(xp);
                float4 x1 = *reinterpret_cast<const float4*>(xp + 4);
                bf16x8 t;
                t[0] = (short)f2bf(x0.x); t[1] = (short)f2bf(x0.y);
                t[2] = (short)f2bf(x0.z); t[3] = (short)f2bf(x0.w);
                t[4] = (short)f2bf(x1.x); t[5] = (short)f2bf(x1.y);
                t[6] = (short)f2bf(x1.z); t[7] = (short)f2bf(x1.w);
                xf[rt][ks] = t;
            }
        }
    }

    // ---- per col-tile: load W frags once, 2 row-tiles of MFMA, packed store -
#pragma unroll
    for (int ct = 0; ct < CT; ++ct) {
        const bf16_t* wp = WT + (size_t)(ct * 16 + col16) * 128 + kgrp * 8;
        bf16x8 wf[4];
#pragma unroll
        for (int ks = 0; ks < 4; ++ks) wf[ks] = *reinterpret_cast<const bf16x8*>(wp + ks * 32);
#pragma unroll
        for (int rt = 0; rt < RT; ++rt) {
            f32x4 acc = {0.f, 0.f, 0.f, 0.f};
#pragma unroll
            for (int ks = 0; ks < 4; ++ks)
                acc = __builtin_amdgcn_mfma_f32_16x16x32_bf16(wf[ks], xf[rt][ks], acc, 0, 0, 0);
            // lane owns out[row[rt]][ct*16 + kgrp*4 + (0..3)]
            if (row[rt] < n) {
                float s = sc[rt];
                uint2 w;
                w.x = f2bf(acc[0] * s) | (f2bf(acc[1] * s) << 16);
                w.y = f2bf(acc[2] * s) | (f2bf(acc[3] * s) << 16);
                if constexpr (OSPLIT) {
                    int half = ct < CT / 2;
                    bf16_t* hb = half ? H : H2;
                    int cc = half ? ct : ct - CT / 2;
                    *reinterpret_cast<uint2*>(hb + (size_t)row[rt] * (OUTC / 2) + cc * 16 + kgrp * 4) = w;
                } else {
                    *reinterpret_cast<uint2*>(H + (size_t)row[rt] * OUTC + ct * 16 + kgrp * 4) = w;
                }
            }
        }
    }
}

// -------------------- CSR aggregate + bias + PReLU (fused, bf16 gather) -----
// out[i,:] = prelu( dinv[i]*(H'[i,:] + sum_j H'[es[j],:]) + b, a )
template <int F, bool OUTBF>
__global__ __launch_bounds__(THREADS) void agg_kernel(const bf16_t* __restrict__ H,
                                                      const float* __restrict__ dinv,
                                                      const int* __restrict__ off,
                                                      const int* __restrict__ cnt,
                                                      const int* __restrict__ es,
                                                      const float* __restrict__ bias,
                                                      const float* __restrict__ a_ptr,
                                                      void* __restrict__ outv, int n) {
    constexpr int TPN = F / 8;                 // threads per node (8 bf16 = 16B each)
    int node = blockIdx.x * (THREADS / TPN) + (int)threadIdx.x / TPN;
    int l8   = (int)threadIdx.x % TPN;
    if (node >= n) return;
    const int fbase = l8 * 8;

    float acc[8];
    {   // self term (H already pre-scaled by dinv[node])
        uint4 v = *reinterpret_cast<const uint4*>(H + (size_t)node * F + fbase);
        acc[0] = bflo(v.x); acc[1] = bfhi(v.x);
        acc[2] = bflo(v.y); acc[3] = bfhi(v.y);
        acc[4] = bflo(v.z); acc[5] = bfhi(v.z);
        acc[6] = bflo(v.w); acc[7] = bfhi(v.w);
    }

    int j0 = off[node];
    int m  = cnt[node];
    int i = 0;
    for (; i + 3 < m; i += 4) {
        int s0 = es[j0 + i], s1 = es[j0 + i + 1], s2 = es[j0 + i + 2], s3 = es[j0 + i + 3];
        uint4 v0 = *reinterpret_cast<const uint4*>(H + (size_t)s0 * F + fbase);
        uint4 v1 = *reinterpret_cast<const uint4*>(H + (size_t)s1 * F + fbase);
        uint4 v2 = *reinterpret_cast<const uint4*>(H + (size_t)s2 * F + fbase);
        uint4 v3 = *reinterpret_cast<const uint4*>(H + (size_t)s3 * F + fbase);
        acc[0] += (bflo(v0.x) + bflo(v1.x)) + (bflo(v2.x) + bflo(v3.x));
        acc[1] += (bfhi(v0.x) + bfhi(v1.x)) + (bfhi(v2.x) + bfhi(v3.x));
        acc[2] += (bflo(v0.y) + bflo(v1.y)) + (bflo(v2.y) + bflo(v3.y));
        acc[3] += (bfhi(v0.y) + bfhi(v1.y)) + (bfhi(v2.y) + bfhi(v3.y));
        acc[4] += (bflo(v0.z) + bflo(v1.z)) + (bflo(v2.z) + bflo(v3.z));
        acc[5] += (bfhi(v0.z) + bfhi(v1.z)) + (bfhi(v2.z) + bfhi(v3.z));
        acc[6] += (bflo(v0.w) + bflo(v1.w)) + (bflo(v2.w) + bflo(v3.w));
        acc[7] += (bfhi(v0.w) + bfhi(v1.w)) + (bfhi(v2.w) + bfhi(v3.w));
    }
    for (; i < m; ++i) {
        int s0 = es[j0 + i];
        uint4 v0 = *reinterpret_cast<const uint4*>(H + (size_t)s0 * F + fbase);
        acc[0] += bflo(v0.x); acc[1] += bfhi(v0.x);
        acc[2] += bflo(v0.y); acc[3] += bfhi(v0.y);
        acc[4] += bflo(v0.z); acc[5] += bfhi(v0.z);
        acc[6] += bflo(v0.w); acc[7] += bfhi(v0.w);
    }

    float di = dinv[node];
    float a  = *a_ptr;
    float4 b0 = *reinterpret_cast<const float4*>(bias + fbase);
    float4 b1 = *reinterpret_cast<const float4*>(bias + fbase + 4);
    float bb[8] = {b0.x, b0.y, b0.z, b0.w, b1.x, b1.y, b1.z, b1.w};
    float o[8];
#pragma unroll
    for (int k = 0; k < 8; ++k) {
        float v = acc[k] * di + bb[k];
        o[k] = v >= 0.f ? v : a * v;
    }

    if constexpr (OUTBF) {
        uint4 w;
        w.x = f2bf(o[0]) | (f2bf(o[1]) << 16);
        w.y = f2bf(o[2]) | (f2bf(o[3]) << 16);
        w.z = f2bf(o[4]) | (f2bf(o[5]) << 16);
        w.w = f2bf(o[6]) | (f2bf(o[7]) << 16);
        *reinterpret_cast<uint4*>((bf16_t*)outv + (size_t)node * F + fbase) = w;
    } else {
        float* op = (float*)outv + (size_t)node * F + fbase;
        *reinterpret_cast<float4*>(op)     = make_float4(o[0], o[1], o[2], o[3]);
        *reinterpret_cast<float4*>(op + 4) = make_float4(o[4], o[5], o[6], o[7]);
    }
}

extern "C" void kernel_launch(void* const* d_in, const int* in_sizes, int n_in,
                              void* d_out, int out_size, void* d_ws, size_t ws_size,
                              hipStream_t stream) {
    const float* x   = (const float*)d_in[0];
    const int*   ei  = (const int*)d_in[1];
    const float* W1  = (const float*)d_in[2];
    const float* b1  = (const float*)d_in[3];
    const float* W2  = (const float*)d_in[4];
    const float* b2  = (const float*)d_in[5];
    const float* a   = (const float*)d_in[6];

    const int IN  = 128;
    const int HID = 128;
    const int OUT = 64;
    const int n = in_sizes[0] / IN;       // 100000
    const int e = in_sizes[1] / 2;        // 1600000
    const int* src = ei;
    const int* dst = ei + e;

    const int K     = (n + BINSZ - 1) >> BINSH;   // 782 bins
    const int chunk = (e + NBLK - 1) / NBLK;      // 6250 edges/block
    const int M     = K * NBLK;                   // ~200k hist entries
    const int nb    = (M + SCAN_CHUNK - 1) / SCAN_CHUNK;

    auto align = [](size_t v) { return (v + 255) / 256 * 256; };
    char* ws = (char*)d_ws;
    size_t o = 0;
    int*          hist   = (int*)(ws + o);          o += align((size_t)M * 4);
    int*          hoff   = (int*)(ws + o);          o += align((size_t)M * 4);
    int*          bsum   = (int*)(ws + o);          o += align((size_t)nb * 4);
    unsigned int* sorted = (unsigned int*)(ws + o); o += align((size_t)e * 4);
    int*          es     = (int*)(ws + o);          o += align((size_t)e * 4);
    float*        dinv   = (float*)(ws + o);        o += align((size_t)n * 4);
    int*          off    = (int*)(ws + o);          o += align((size_t)n * 4);
    int*          cnt    = (int*)(ws + o);          o += align((size_t)n * 4);
    bf16_t*       h1a    = (bf16_t*)(ws + o);       o += align((size_t)n * 64 * 2);
    bf16_t*       h1b    = (bf16_t*)(ws + o);       o += align((size_t)n * 64 * 2);
    bf16_t*       h2a    = (bf16_t*)(ws + o);       o += align((size_t)n * 64 * 2);
    bf16_t*       h2b    = (bf16_t*)(ws + o);       o += align((size_t)n * 64 * 2);
    bf16_t*       g      = (bf16_t*)(ws + o);       o += align((size_t)n * OUT * 2);
    bf16_t*       WT1    = (bf16_t*)(ws + o);       o += align((size_t)IN * HID * 2);
    bf16_t*       WT2    = (bf16_t*)(ws + o);       o += align((size_t)HID * OUT * 2);

    float* out = (float*)d_out;

    // ---- W transposes (one dispatch, independent of CSR chain) ----
    {
        int tot = IN * HID + HID * OUT;
        wt2_kernel<<<(tot + THREADS - 1) / THREADS, THREADS, 0, stream>>>(
            W1, WT1, W2, WT2, IN, HID, HID, OUT);
    }

    // ---- CSR build: radix partition + per-bin counting sort ----
    hist_kernel<<<NBLK, RSTH, 0, stream>>>(dst, hist, e, K, chunk);
    scan_phaseA_kernel<<<nb, THREADS, 0, stream>>>(hist, bsum, M);
    scan_phaseB_kernel<<<1, THREADS, 0, stream>>>(bsum, nb);
    scan_phaseC_kernel<<<nb, THREADS, 0, stream>>>(hist, bsum, hoff, M);
    rank_scatter_kernel<<<NBLK, RSTH, 0, stream>>>(src, dst, hoff, sorted, e, K, chunk);
    bin_build_kernel<<<K, RSTH, 0, stream>>>(sorted, hoff, dinv, off, cnt, es, n, e, K);

    int gbG = (n + 127) / 128;                 // 128 rows/block (4 waves x 32)
    constexpr int NPB = THREADS / (64 / 8);    // 32 nodes/block for agg<64>
    int gbA = (n + NPB - 1) / NPB;

    // ---- layer 1: GEMM -> planar halves; two half-aggregations ----
    gemm_mfma_kernel<128, false, false, true><<<gbG, THREADS, 0, stream>>>(
        x, nullptr, WT1, dinv, h1a, h1b, n);
    agg_kernel<64, true><<<gbA, THREADS, 0, stream>>>(h1a, dinv, off, cnt, es, b1,      a, h2a, n);
    agg_kernel<64, true><<<gbA, THREADS, 0, stream>>>(h1b, dinv, off, cnt, es, b1 + 64, a, h2b, n);

    // ---- layer 2 ----
    gemm_mfma_kernel<64, true, true, false><<<gbG, THREADS, 0, stream>>>(
        h2a, h2b, WT2, dinv, g, nullptr, n);
    agg_kernel<64, false><<<gbA, THREADS, 0, stream>>>(g, dinv, off, cnt, es, b2, a, out, n);

    (void)ws_size; (void)n_in; (void)out_size;
}